// Round 1
// 599.557 us; speedup vs baseline: 1.0452x; 1.0452x over previous
//
#include <hip/hip_runtime.h>
#include <math.h>

#define N_NODES 10000
#define IN_FEAT 512
#define OUT_FEAT 64
#define LRELU_ALPHA 0.2f
#define HUB_THRESH 0.01f
#define BITS_WORDS 320   // ceil(10000/32)=313, padded to 320 (10 iters x 32 words)
#define CAND_CAP 1024    // per-row full-row list; ~100 expected survivors; exact fallback on overflow

// workspace layout, in 32-bit words
#define WH_OFF   0          // Wh [10000*64]
#define ESRC_OFF 640000     // e_src [10000]
#define EDST_OFF 650000     // e_dst [10000]
#define T_OFF    660000     // t_j = hub[j]*0.01 [10000]
#define LT_OFF   670000     // log(t_j) [10000]

// ---------------------------------------------------------------------------
// Kernel 1: Wh = h @ W  (10000x512x64), e_src = Wh@a_src, e_dst = Wh@a_dst,
// plus (in trailing blocks) t_j and log(t_j) from hub_mask.
// Staging vectorized to float4 (4x fewer staging instrs); compute unchanged.
// ---------------------------------------------------------------------------
__global__ __launch_bounds__(256) void k1_gemm(
    const float* __restrict__ h, const float* __restrict__ W,
    const float* __restrict__ a_src, const float* __restrict__ a_dst,
    const float* __restrict__ hub, float* __restrict__ ws)
{
    const int bx = blockIdx.x, tid = threadIdx.x;
    if (bx >= 625) {
        const int base = (bx - 625) * 1024;
        #pragma unroll
        for (int e = 0; e < 4; ++e) {
            int idx = base + e * 256 + tid;
            if (idx < N_NODES) {
                float t = hub[idx] * HUB_THRESH;
                ws[T_OFF + idx]  = t;
                ws[LT_OFF + idx] = logf(t);   // hub==0 -> -inf: prefilter passes, relu decides
            }
        }
        return;
    }

    __shared__ __align__(16) float Ws[64 * 64];   // [kk][col]
    __shared__ __align__(16) float Hs[16 * 64];   // [r][kk]
    const int col = tid & 63, rg = tid >> 6;
    const int rowBase = bx * 16;                  // 625*16 == 10000 exactly
    float acc[4] = {0.f, 0.f, 0.f, 0.f};

    for (int k0 = 0; k0 < IN_FEAT; k0 += 64) {
        // W tile: 4096 contiguous floats starting at W + k0*64 -> 1024 float4
        const float4* __restrict__ W4 = (const float4*)(W + (size_t)k0 * 64);
        float4* Ws4 = (float4*)Ws;
        #pragma unroll
        for (int t = 0; t < 4; ++t) Ws4[tid + t * 256] = W4[tid + t * 256];
        // H tile: 16 rows x 64 cols = 256 float4; thread tid -> row tid>>4, quad tid&15
        ((float4*)Hs)[tid] =
            *(const float4*)&h[(size_t)(rowBase + (tid >> 4)) * IN_FEAT + k0 + (tid & 15) * 4];
        __syncthreads();
        #pragma unroll
        for (int k4 = 0; k4 < 16; ++k4) {
            float4 hv0 = *(const float4*)&Hs[(rg + 0)  * 64 + k4 * 4];
            float4 hv1 = *(const float4*)&Hs[(rg + 4)  * 64 + k4 * 4];
            float4 hv2 = *(const float4*)&Hs[(rg + 8)  * 64 + k4 * 4];
            float4 hv3 = *(const float4*)&Hs[(rg + 12) * 64 + k4 * 4];
            float w0 = Ws[(k4 * 4 + 0) * 64 + col];
            float w1 = Ws[(k4 * 4 + 1) * 64 + col];
            float w2 = Ws[(k4 * 4 + 2) * 64 + col];
            float w3 = Ws[(k4 * 4 + 3) * 64 + col];
            acc[0] += hv0.x * w0 + hv0.y * w1 + hv0.z * w2 + hv0.w * w3;
            acc[1] += hv1.x * w0 + hv1.y * w1 + hv1.z * w2 + hv1.w * w3;
            acc[2] += hv2.x * w0 + hv2.y * w1 + hv2.z * w2 + hv2.w * w3;
            acc[3] += hv3.x * w0 + hv3.y * w1 + hv3.z * w2 + hv3.w * w3;
        }
        __syncthreads();
    }

    const float asv = a_src[col], adv = a_dst[col];
    #pragma unroll
    for (int r = 0; r < 4; ++r) {
        int row = rowBase + rg + 4 * r;
        ws[WH_OFF + (size_t)row * 64 + col] = acc[r];
        float s1 = acc[r] * asv, s2 = acc[r] * adv;
        #pragma unroll
        for (int m = 32; m; m >>= 1) {
            s1 += __shfl_xor(s1, m, 64);
            s2 += __shfl_xor(s2, m, 64);
        }
        if (col == 0) {
            ws[ESRC_OFF + row] = s1;
            ws[EDST_OFF + row] = s2;
        }
    }
}

// ---------------------------------------------------------------------------
// Kernel 2 (fused, 2 rows/block): block b handles rows 2b, 2b+1.
// Pass A: stream both adj rows once (400 MB total); bits built via __ballot
//   (no ds_swizzle chains); unroll-3 over 9 unguarded iters + guarded tail
//   (tail loads zeroed so ballot/write run full-wave).
//   Bit layout: ballot-major. bits[r], b64 slot (it*16 + w*4 + c) holds the
//   64-lane ballot of component c for wave w, iter it. j for (it,w,lane,c)
//   = it*1024 + w*256 + lane*4 + c.
// Pass B: ONE barrier-free produce pass with the FULL log-domain prefilter
//   e > thr + lt_j (per-j lt required: lt unbounded below, no lt-free bound
//   is valid — R6 lesson); survivors -> single per-row list (atomic append,
//   cap 1024, exact LDS-atomic overflow fallback); then ONE barrier; then a
//   4-way-unrolled consume (4 cand reads + 4 independent 256B Wh loads in
//   flight per step). Replaces 10 barrier-coupled chunk loops whose serial
//   ds_read->global_load chains were the dominant stall.
// LDS ~19.5 KB -> 8 blocks/CU. Epilogue aliases `bits`.
// ---------------------------------------------------------------------------
__global__ __launch_bounds__(256) void k2_fused(
    const int* __restrict__ adj, const float* __restrict__ ws,
    float* __restrict__ out)
{
    const int b = blockIdx.x, tid = threadIdx.x;
    const int lane = tid & 63, w = tid >> 6;
    const int i0 = 2 * b, i1 = 2 * b + 1;
    __shared__ unsigned bits[2][BITS_WORDS];   // 2560 B; aliased as partB in epilogue
    __shared__ float partA[2][4];
    __shared__ int2  cand[2][CAND_CAP];        // 16 KB
    __shared__ int   cnt[2];
    __shared__ float oaccL[2][64];             // overflow accumulator (exact fallback)

    const float esrc0 = ws[ESRC_OFF + i0];
    const float esrc1 = ws[ESRC_OFF + i1];
    const float* __restrict__ edst = ws + EDST_OFF;
    const int4* __restrict__ arow0 = (const int4*)(adj + (size_t)i0 * N_NODES); // 40000 B rows: 16B aligned
    const int4* __restrict__ arow1 = (const int4*)(adj + (size_t)i1 * N_NODES);
    float acc0 = 0.f, acc1 = 0.f;

    if (tid < 2) cnt[tid] = 0;                 // visible after pass-A barrier
    if (tid < 128) ((float*)oaccL)[tid] = 0.f;

    // ---- Pass A ----
#define PA_BODY(IT, A0, A1, E4)                                              \
    {                                                                        \
        float s, e, ex;                                                      \
        s = esrc0 + (E4).x; e = fmaxf(s, LRELU_ALPHA * s); ex = __expf(e);   \
        if ((A0).x > 0) acc0 += ex;                                          \
        unsigned long long B0 = __ballot((A0).x > 0);                        \
        s = esrc0 + (E4).y; e = fmaxf(s, LRELU_ALPHA * s); ex = __expf(e);   \
        if ((A0).y > 0) acc0 += ex;                                          \
        unsigned long long B1 = __ballot((A0).y > 0);                        \
        s = esrc0 + (E4).z; e = fmaxf(s, LRELU_ALPHA * s); ex = __expf(e);   \
        if ((A0).z > 0) acc0 += ex;                                          \
        unsigned long long B2 = __ballot((A0).z > 0);                        \
        s = esrc0 + (E4).w; e = fmaxf(s, LRELU_ALPHA * s); ex = __expf(e);   \
        if ((A0).w > 0) acc0 += ex;                                          \
        unsigned long long B3 = __ballot((A0).w > 0);                        \
        s = esrc1 + (E4).x; e = fmaxf(s, LRELU_ALPHA * s); ex = __expf(e);   \
        if ((A1).x > 0) acc1 += ex;                                          \
        unsigned long long B4 = __ballot((A1).x > 0);                        \
        s = esrc1 + (E4).y; e = fmaxf(s, LRELU_ALPHA * s); ex = __expf(e);   \
        if ((A1).y > 0) acc1 += ex;                                          \
        unsigned long long B5 = __ballot((A1).y > 0);                        \
        s = esrc1 + (E4).z; e = fmaxf(s, LRELU_ALPHA * s); ex = __expf(e);   \
        if ((A1).z > 0) acc1 += ex;                                          \
        unsigned long long B6 = __ballot((A1).z > 0);                        \
        s = esrc1 + (E4).w; e = fmaxf(s, LRELU_ALPHA * s); ex = __expf(e);   \
        if ((A1).w > 0) acc1 += ex;                                          \
        unsigned long long B7 = __ballot((A1).w > 0);                        \
        if (lane < 8) {                                                      \
            /* lane -> (r = lane>>2, c = lane&3); ballots are wave-uniform */\
            unsigned long long v =                                           \
                (lane & 4) ? ((lane & 2) ? ((lane & 1) ? B7 : B6)            \
                                         : ((lane & 1) ? B5 : B4))           \
                           : ((lane & 2) ? ((lane & 1) ? B3 : B2)            \
                                         : ((lane & 1) ? B1 : B0));          \
            *((unsigned long long*)&bits[lane >> 2][0] +                     \
              ((IT) * 16 + w * 4 + (lane & 3))) = v;                         \
        }                                                                    \
    }

    // iters 0..8: max j = 8*1024 + 255*4 + 3 = 9215 < 10000 -> unguarded
    #pragma unroll 3
    for (int it = 0; it < 9; ++it) {
        int4 a0 = arow0[it * 256 + tid];
        int4 a1 = arow1[it * 256 + tid];
        float4 e4 = *(const float4*)(edst + it * 1024 + tid * 4);
        PA_BODY(it, a0, a1, e4)
    }
    {   // tail it=9: guarded loads, zeros for OOB lanes so ballot/write are full-wave
        const int j0 = 9216 + tid * 4;
        int4 a0 = make_int4(0, 0, 0, 0), a1 = make_int4(0, 0, 0, 0);
        float4 e4 = make_float4(0.f, 0.f, 0.f, 0.f);
        if (j0 < N_NODES) {
            a0 = arow0[9 * 256 + tid];
            a1 = arow1[9 * 256 + tid];
            e4 = *(const float4*)(edst + j0);
        }
        PA_BODY(9, a0, a1, e4)
    }
#undef PA_BODY

    #pragma unroll
    for (int m = 32; m; m >>= 1) {
        acc0 += __shfl_xor(acc0, m, 64);
        acc1 += __shfl_xor(acc1, m, 64);
    }
    if (lane == 0) { partA[0][w] = acc0; partA[1][w] = acc1; }
    __syncthreads();
    const float l0 = partA[0][0] + partA[0][1] + partA[0][2] + partA[0][3];
    const float l1 = partA[1][0] + partA[1][1] + partA[1][2] + partA[1][3];

    // ---- Pass B: produce (no barriers) ----
    const bool empty0 = (l0 == 0.0f), empty1 = (l1 == 0.0f);  // rows w/o neighbors: uniform 1/N
    const float cl0 = empty0 ? 0.0f : logf(l0);
    const float cl1 = empty1 ? 0.0f : logf(l1);
    const float thr0 = cl0 - 0.0625f, thr1 = cl1 - 0.0625f;   // prefilter slack
    const float invN = 1.0f / (float)N_NODES;
    const float* __restrict__ tarr  = ws + T_OFF;
    const float* __restrict__ ltarr = ws + LT_OFF;
    const float* __restrict__ Wh    = ws + WH_OFF;
    float oacc0 = 0.f, oacc1 = 0.f;
    const unsigned rm0 = empty0 ? 0u : 0xffffffffu;
    const unsigned rm1 = empty1 ? 0u : 0xffffffffu;
    const unsigned lb = lane & 31;

#define PB_TEST(WROW, ESRC, THR, CL, R, ED, LT, JC)                          \
    if (((WROW) >> lb) & 1u) {                                               \
        float s = (ESRC) + (ED);                                             \
        float e = fmaxf(s, LRELU_ALPHA * s);                                 \
        if (e > (THR) + (LT)) {                          /* rare */          \
            float p = __expf(e - (CL));                  /* = exp(e)/l */    \
            float wgt = p - tarr[JC];                    /* exact relu */    \
            if (wgt > 0.0f) {                                                \
                int k = atomicAdd(&cnt[R], 1);                               \
                if (k < CAND_CAP) {                                          \
                    cand[R][k] = make_int2((JC), __float_as_int(wgt));       \
                } else {   /* exact fallback; never taken on plausible data */\
                    const float* whp = Wh + (size_t)(JC) * 64;               \
                    for (int cc = 0; cc < 64; ++cc)                          \
                        atomicAdd(&oaccL[R][cc], wgt * whp[cc]);             \
                }                                                            \
            }                                                                \
        }                                                                    \
    }

    #pragma unroll 2
    for (int it = 0; it < 10; ++it) {
        const int j0 = it * 1024 + tid * 4;
        if (j0 < N_NODES) {
            const int wb = it * 32 + w * 8 + (lane >> 5);
            const unsigned w00 = bits[0][wb + 0] & rm0;
            const unsigned w01 = bits[0][wb + 2] & rm0;
            const unsigned w02 = bits[0][wb + 4] & rm0;
            const unsigned w03 = bits[0][wb + 6] & rm0;
            const unsigned w10 = bits[1][wb + 0] & rm1;
            const unsigned w11 = bits[1][wb + 2] & rm1;
            const unsigned w12 = bits[1][wb + 4] & rm1;
            const unsigned w13 = bits[1][wb + 6] & rm1;
            if (((w00 | w01 | w02 | w03 | w10 | w11 | w12 | w13) >> lb) & 1u) {
                float4 e4  = *(const float4*)(edst + j0);
                float4 lt4 = *(const float4*)(ltarr + j0);
                PB_TEST(w00, esrc0, thr0, cl0, 0, e4.x, lt4.x, j0 + 0)
                PB_TEST(w10, esrc1, thr1, cl1, 1, e4.x, lt4.x, j0 + 0)
                PB_TEST(w01, esrc0, thr0, cl0, 0, e4.y, lt4.y, j0 + 1)
                PB_TEST(w11, esrc1, thr1, cl1, 1, e4.y, lt4.y, j0 + 1)
                PB_TEST(w02, esrc0, thr0, cl0, 0, e4.z, lt4.z, j0 + 2)
                PB_TEST(w12, esrc1, thr1, cl1, 1, e4.z, lt4.z, j0 + 2)
                PB_TEST(w03, esrc0, thr0, cl0, 0, e4.w, lt4.w, j0 + 3)
                PB_TEST(w13, esrc1, thr1, cl1, 1, e4.w, lt4.w, j0 + 3)
            }
        }
        if ((empty0 | empty1) && j0 < N_NODES) {   // block-uniform; dead for this data
            float4 t4 = *(const float4*)(tarr + j0);
            #pragma unroll
            for (int c = 0; c < 4; ++c) {
                float tv = (c == 0) ? t4.x : (c == 1) ? t4.y : (c == 2) ? t4.z : t4.w;
                float wv = invN - tv;
                if (wv > 0.0f) {
                    #pragma unroll
                    for (int r = 0; r < 2; ++r) {
                        if (r == 0 ? empty0 : empty1) {
                            int k = atomicAdd(&cnt[r], 1);
                            if (k < CAND_CAP) {
                                cand[r][k] = make_int2(j0 + c, __float_as_int(wv));
                            } else {
                                const float* whp = Wh + (size_t)(j0 + c) * 64;
                                for (int cc = 0; cc < 64; ++cc)
                                    atomicAdd(&oaccL[r][cc], wv * whp[cc]);
                            }
                        }
                    }
                }
            }
        }
    }
#undef PB_TEST

    // ---- one barrier, then batched consume (4-deep MLP) ----
    __syncthreads();
    const int M0 = min(cnt[0], CAND_CAP), M1 = min(cnt[1], CAND_CAP);

    int c0 = w;
    for (; c0 + 12 < M0; c0 += 16) {
        int2 cd0 = cand[0][c0];
        int2 cd1 = cand[0][c0 + 4];
        int2 cd2 = cand[0][c0 + 8];
        int2 cd3 = cand[0][c0 + 12];
        float v0 = Wh[(size_t)cd0.x * 64 + lane];   // 256B coalesced, L2-hit
        float v1 = Wh[(size_t)cd1.x * 64 + lane];
        float v2 = Wh[(size_t)cd2.x * 64 + lane];
        float v3 = Wh[(size_t)cd3.x * 64 + lane];
        oacc0 += __int_as_float(cd0.y) * v0;
        oacc0 += __int_as_float(cd1.y) * v1;
        oacc0 += __int_as_float(cd2.y) * v2;
        oacc0 += __int_as_float(cd3.y) * v3;
    }
    for (; c0 < M0; c0 += 4) {
        int2 cd = cand[0][c0];
        oacc0 += __int_as_float(cd.y) * Wh[(size_t)cd.x * 64 + lane];
    }
    int c1 = w;
    for (; c1 + 12 < M1; c1 += 16) {
        int2 cd0 = cand[1][c1];
        int2 cd1 = cand[1][c1 + 4];
        int2 cd2 = cand[1][c1 + 8];
        int2 cd3 = cand[1][c1 + 12];
        float v0 = Wh[(size_t)cd0.x * 64 + lane];
        float v1 = Wh[(size_t)cd1.x * 64 + lane];
        float v2 = Wh[(size_t)cd2.x * 64 + lane];
        float v3 = Wh[(size_t)cd3.x * 64 + lane];
        oacc1 += __int_as_float(cd0.y) * v0;
        oacc1 += __int_as_float(cd1.y) * v1;
        oacc1 += __int_as_float(cd2.y) * v2;
        oacc1 += __int_as_float(cd3.y) * v3;
    }
    for (; c1 < M1; c1 += 4) {
        int2 cd = cand[1][c1];
        oacc1 += __int_as_float(cd.y) * Wh[(size_t)cd.x * 64 + lane];
    }

    // epilogue: alias bits (2560 B >= 512 floats). Safe: the pre-consume
    // barrier guarantees all produce-phase reads of `bits` are done; consume
    // touches only cand/Wh.
    float* partB = (float*)bits;
    partB[tid]       = oacc0;
    partB[256 + tid] = oacc1;
    __syncthreads();
    if (w < 2) {
        const float* pb = partB + w * 256;
        float tot = pb[lane] + pb[64 + lane] + pb[128 + lane] + pb[192 + lane]
                  + oaccL[w][lane];
        out[(size_t)(i0 + w) * 64 + lane] = tot > 0.0f ? tot : expm1f(tot);   // elu, alpha=1
    }
}

// ---------------------------------------------------------------------------
extern "C" void kernel_launch(void* const* d_in, const int* in_sizes, int n_in,
                              void* d_out, int out_size, void* d_ws, size_t ws_size,
                              hipStream_t stream)
{
    const float* h     = (const float*)d_in[0];
    const float* W     = (const float*)d_in[1];
    const float* a_src = (const float*)d_in[2];
    const float* a_dst = (const float*)d_in[3];
    const float* hub   = (const float*)d_in[4];
    const int*   adj   = (const int*)d_in[5];
    float* ws  = (float*)d_ws;
    float* out = (float*)d_out;

    k1_gemm<<<635, 256, 0, stream>>>(h, W, a_src, a_dst, hub, ws);
    k2_fused<<<N_NODES / 2, 256, 0, stream>>>(adj, ws, out);
}

// Round 2
// 592.038 us; speedup vs baseline: 1.0585x; 1.0127x over previous
//
#include <hip/hip_runtime.h>
#include <math.h>

#define N_NODES 10000
#define IN_FEAT 512
#define OUT_FEAT 64
#define LRELU_ALPHA 0.2f
#define HUB_THRESH 0.01f
#define BITS_WORDS 320   // ceil(10000/32)=313, padded to 320 (10 iters x 32 words)
#define CAND_CAP 1024    // per-row full-row list; ~100 expected survivors; exact fallback on overflow
#define PREF_SLACK 0.9394131f   // exp(-0.0625): prefilter slack, must not false-reject

// workspace layout, in 32-bit words
#define WH_OFF   0          // Wh [10000*64]
#define ESRC_OFF 640000     // e_src [10000]
#define EDST_OFF 650000     // e_dst [10000]
#define T_OFF    660000     // t_j = hub[j]*0.01 [10000]
#define F1_OFF   670000     // exp(edst_j)
#define F2_OFF   680000     // exp(0.2*edst_j)
#define AL_OFF   690000     // alpha_j = F1_j / t_j
#define BE_OFF   700000     // beta_j  = F2_j / t_j

// ---------------------------------------------------------------------------
// Kernel 1: Wh = h @ W (10000x512x64), e_src = Wh@a_src, e_dst = Wh@a_dst.
// Thread mapping: 4 cols x 1 row per thread -> Ws read as 4x ds_read_b128
// (was 4x ds_read_b32): ~40% fewer LDS-pipe cycles (k1's modeled bottleneck).
// Hs padded to stride 68 floats so the 4-row broadcast spreads across banks.
// ---------------------------------------------------------------------------
__global__ __launch_bounds__(256) void k1_gemm(
    const float* __restrict__ h, const float* __restrict__ W,
    const float* __restrict__ a_src, const float* __restrict__ a_dst,
    float* __restrict__ ws)
{
    const int bx = blockIdx.x, tid = threadIdx.x;
    __shared__ __align__(16) float Ws[64 * 64];   // [kk][col]
    __shared__ __align__(16) float Hs[16 * 68];   // [r][kk], padded stride 68
    const int row_l = tid >> 4;                   // 0..15
    const int q     = tid & 15;                   // quad index
    const int c4    = q * 4;                      // col 0,4,...,60
    const int row   = bx * 16 + row_l;            // 625*16 == 10000 exactly
    float4 acc = make_float4(0.f, 0.f, 0.f, 0.f);

    for (int k0 = 0; k0 < IN_FEAT; k0 += 64) {
        const float4* __restrict__ W4 = (const float4*)(W + (size_t)k0 * 64);
        float4* Ws4 = (float4*)Ws;
        #pragma unroll
        for (int t = 0; t < 4; ++t) Ws4[tid + t * 256] = W4[tid + t * 256];
        *(float4*)&Hs[row_l * 68 + c4] =
            *(const float4*)&h[(size_t)row * IN_FEAT + k0 + c4];
        __syncthreads();
        #pragma unroll
        for (int k4 = 0; k4 < 16; ++k4) {
            float4 hv = *(const float4*)&Hs[row_l * 68 + k4 * 4];          // broadcast
            float4 w0 = *(const float4*)&Ws[(k4 * 4 + 0) * 64 + c4];      // b128, conflict-free
            float4 w1 = *(const float4*)&Ws[(k4 * 4 + 1) * 64 + c4];
            float4 w2 = *(const float4*)&Ws[(k4 * 4 + 2) * 64 + c4];
            float4 w3 = *(const float4*)&Ws[(k4 * 4 + 3) * 64 + c4];
            acc.x += hv.x * w0.x + hv.y * w1.x + hv.z * w2.x + hv.w * w3.x;
            acc.y += hv.x * w0.y + hv.y * w1.y + hv.z * w2.y + hv.w * w3.y;
            acc.z += hv.x * w0.z + hv.y * w1.z + hv.z * w2.z + hv.w * w3.z;
            acc.w += hv.x * w0.w + hv.y * w1.w + hv.z * w2.w + hv.w * w3.w;
        }
        __syncthreads();
    }

    *(float4*)&ws[WH_OFF + (size_t)row * 64 + c4] = acc;
    const float4 as4 = *(const float4*)&a_src[c4];   // a_src is 64 contiguous floats
    const float4 ad4 = *(const float4*)&a_dst[c4];
    float s1 = acc.x * as4.x + acc.y * as4.y + acc.z * as4.z + acc.w * as4.w;
    float s2 = acc.x * ad4.x + acc.y * ad4.y + acc.z * ad4.z + acc.w * ad4.w;
    // reduce across the 16 lanes sharing a row (xor masks stay in-group)
    #pragma unroll
    for (int m = 1; m <= 8; m <<= 1) {
        s1 += __shfl_xor(s1, m, 64);
        s2 += __shfl_xor(s2, m, 64);
    }
    if (q == 0) {
        ws[ESRC_OFF + row] = s1;
        ws[EDST_OFF + row] = s2;
    }
}

// ---------------------------------------------------------------------------
// Kernel 1b: per-j precompute (after k1 so edst is final, before k2).
// F1=exp(edst), F2=exp(0.2*edst), t=hub*0.01, alpha=F1/t, beta=F2/t.
// t==0 -> alpha/beta=+inf: prefilter passes, exact relu decides (correct).
// ---------------------------------------------------------------------------
__global__ __launch_bounds__(256) void k1b_prep(
    const float* __restrict__ hub, float* __restrict__ ws)
{
    const int j = blockIdx.x * 256 + threadIdx.x;
    if (j < N_NODES) {
        float ed = ws[EDST_OFF + j];
        float F1 = __expf(ed);
        float F2 = __expf(0.2f * ed);
        float t  = hub[j] * HUB_THRESH;
        ws[F1_OFF + j] = F1;
        ws[F2_OFF + j] = F2;
        ws[T_OFF  + j] = t;
        ws[AL_OFF + j] = F1 / t;
        ws[BE_OFF + j] = F2 / t;
    }
}

// ---------------------------------------------------------------------------
// Kernel 2 (fused, 2 rows/block): block b handles rows 2b, 2b+1.
// ALGEBRAIC CORE: exp(lrelu(esrc_i+edst_j)) = max(E1_i*F1_j, E2_i*F2_j)
// (exp is monotone; lrelu = max(s, 0.2s)), E1=exp(esrc), E2=exp(0.2 esrc).
// Pass A: stream both adj rows once (400 MB); per element: mul+max+masked-add
//   — ZERO exp calls (was 1e8 chip-wide). Bits via __ballot, layout as R1.
// Pass B: prefilter exp(e) > kappa*l*t_j  <=>  alpha_j > kappa*l/E1 ||
//   beta_j > kappa*l/E2 — two compares per element-row, no log/lt needed.
//   (Per-j test still required: t unbounded below — R6 lesson.) Survivors
//   (rare) run the EXACT original path p=exp(e-cl), wgt=p-t, so final
//   numerics are unchanged. Single list, one barrier, 4-deep consume.
// LDS ~19.5 KB -> 8 blocks/CU.
// ---------------------------------------------------------------------------
__global__ __launch_bounds__(256) void k2_fused(
    const int* __restrict__ adj, const float* __restrict__ ws,
    float* __restrict__ out)
{
    const int b = blockIdx.x, tid = threadIdx.x;
    const int lane = tid & 63, w = tid >> 6;
    const int i0 = 2 * b, i1 = 2 * b + 1;
    __shared__ unsigned bits[2][BITS_WORDS];   // 2560 B; aliased as partB in epilogue
    __shared__ float partA[2][4];
    __shared__ int2  cand[2][CAND_CAP];        // 16 KB
    __shared__ int   cnt[2];
    __shared__ float oaccL[2][64];             // overflow accumulator (exact fallback)

    const float esrc0 = ws[ESRC_OFF + i0];
    const float esrc1 = ws[ESRC_OFF + i1];
    const float E1_0 = __expf(esrc0), E2_0 = __expf(0.2f * esrc0);
    const float E1_1 = __expf(esrc1), E2_1 = __expf(0.2f * esrc1);
    const float R0 = E2_0 / E1_0, R1 = E2_1 / E1_1;   // = exp(-0.8*esrc)
    const int4*   __restrict__ arow0 = (const int4*)(adj + (size_t)i0 * N_NODES);
    const int4*   __restrict__ arow1 = (const int4*)(adj + (size_t)i1 * N_NODES);
    const float4* __restrict__ F14   = (const float4*)(ws + F1_OFF);
    const float4* __restrict__ F24   = (const float4*)(ws + F2_OFF);
    float acc0 = 0.f, acc1 = 0.f;

    if (tid < 2) cnt[tid] = 0;                 // visible after pass-A barrier
    if (tid < 128) ((float*)oaccL)[tid] = 0.f;

    // ---- Pass A: acc_r = sum_{adj} max(F1_j, R_r*F2_j); l_r = E1_r*acc_r ----
#define PA_BODY(IT, A0v, A1v, F1v, F2v)                                      \
    {                                                                        \
        float v0, v1;                                                        \
        unsigned long long B0, B1, B2, B3, B4, B5, B6, B7;                   \
        v0 = fmaxf((F1v).x, R0 * (F2v).x);                                   \
        v1 = fmaxf((F1v).x, R1 * (F2v).x);                                   \
        if ((A0v).x > 0) acc0 += v0;                                         \
        if ((A1v).x > 0) acc1 += v1;                                         \
        B0 = __ballot((A0v).x > 0);                                          \
        B4 = __ballot((A1v).x > 0);                                          \
        v0 = fmaxf((F1v).y, R0 * (F2v).y);                                   \
        v1 = fmaxf((F1v).y, R1 * (F2v).y);                                   \
        if ((A0v).y > 0) acc0 += v0;                                         \
        if ((A1v).y > 0) acc1 += v1;                                         \
        B1 = __ballot((A0v).y > 0);                                          \
        B5 = __ballot((A1v).y > 0);                                          \
        v0 = fmaxf((F1v).z, R0 * (F2v).z);                                   \
        v1 = fmaxf((F1v).z, R1 * (F2v).z);                                   \
        if ((A0v).z > 0) acc0 += v0;                                         \
        if ((A1v).z > 0) acc1 += v1;                                         \
        B2 = __ballot((A0v).z > 0);                                          \
        B6 = __ballot((A1v).z > 0);                                          \
        v0 = fmaxf((F1v).w, R0 * (F2v).w);                                   \
        v1 = fmaxf((F1v).w, R1 * (F2v).w);                                   \
        if ((A0v).w > 0) acc0 += v0;                                         \
        if ((A1v).w > 0) acc1 += v1;                                         \
        B3 = __ballot((A0v).w > 0);                                          \
        B7 = __ballot((A1v).w > 0);                                          \
        if (lane < 8) {                                                      \
            /* lane -> (r = lane>>2, c = lane&3); ballots are wave-uniform */\
            unsigned long long v =                                           \
                (lane & 4) ? ((lane & 2) ? ((lane & 1) ? B7 : B6)            \
                                         : ((lane & 1) ? B5 : B4))           \
                           : ((lane & 2) ? ((lane & 1) ? B3 : B2)            \
                                         : ((lane & 1) ? B1 : B0));          \
            *((unsigned long long*)&bits[lane >> 2][0] +                     \
              ((IT) * 16 + w * 4 + (lane & 3))) = v;                         \
        }                                                                    \
    }

    // iters 0..8: max j = 8*1024 + 255*4 + 3 = 9215 < 10000 -> unguarded
    #pragma unroll 3
    for (int it = 0; it < 9; ++it) {
        int4   a0 = arow0[it * 256 + tid];
        int4   a1 = arow1[it * 256 + tid];
        float4 f1 = F14[it * 256 + tid];
        float4 f2 = F24[it * 256 + tid];
        PA_BODY(it, a0, a1, f1, f2)
    }
    {   // tail it=9: guarded loads, zeros for OOB lanes so ballot/write are full-wave
        const int j0t = 9216 + tid * 4;
        int4   a0 = make_int4(0, 0, 0, 0), a1 = make_int4(0, 0, 0, 0);
        float4 f1 = make_float4(0.f, 0.f, 0.f, 0.f), f2 = f1;
        if (j0t < N_NODES) {
            a0 = arow0[9 * 256 + tid];
            a1 = arow1[9 * 256 + tid];
            f1 = F14[9 * 256 + tid];
            f2 = F24[9 * 256 + tid];
        }
        PA_BODY(9, a0, a1, f1, f2)
    }
#undef PA_BODY

    #pragma unroll
    for (int m = 32; m; m >>= 1) {
        acc0 += __shfl_xor(acc0, m, 64);
        acc1 += __shfl_xor(acc1, m, 64);
    }
    if (lane == 0) { partA[0][w] = acc0; partA[1][w] = acc1; }
    __syncthreads();
    const float l0 = E1_0 * (partA[0][0] + partA[0][1] + partA[0][2] + partA[0][3]);
    const float l1 = E1_1 * (partA[1][0] + partA[1][1] + partA[1][2] + partA[1][3]);

    // ---- Pass B: produce (no barriers) ----
    const bool empty0 = (l0 == 0.0f), empty1 = (l1 == 0.0f);  // rows w/o neighbors: uniform 1/N
    const float cl0 = empty0 ? 0.0f : logf(l0);
    const float cl1 = empty1 ? 0.0f : logf(l1);
    const float A0 = PREF_SLACK * l0 / E1_0, B0v = PREF_SLACK * l0 / E2_0;
    const float A1 = PREF_SLACK * l1 / E1_1, B1v = PREF_SLACK * l1 / E2_1;
    const float invN = 1.0f / (float)N_NODES;
    const float* __restrict__ tarr = ws + T_OFF;
    const float* __restrict__ edst = ws + EDST_OFF;
    const float* __restrict__ alp  = ws + AL_OFF;
    const float* __restrict__ bet  = ws + BE_OFF;
    const float* __restrict__ Wh   = ws + WH_OFF;
    float oacc0 = 0.f, oacc1 = 0.f;
    const unsigned rm0 = empty0 ? 0u : 0xffffffffu;
    const unsigned rm1 = empty1 ? 0u : 0xffffffffu;
    const unsigned lb = lane & 31;

#define PB_TEST(WROW, Athr, Bthr, ESRC, CL, R, ALc, BEc, JC)                 \
    if ((((WROW) >> lb) & 1u) && ((ALc) > (Athr) || (BEc) > (Bthr))) {       \
        float ed = edst[JC];                                                 \
        float s = (ESRC) + ed;                                               \
        float e = fmaxf(s, LRELU_ALPHA * s);                                 \
        float p = __expf(e - (CL));                     /* = exp(e)/l */     \
        float wgt = p - tarr[JC];                       /* exact relu */     \
        if (wgt > 0.0f) {                                                    \
            int k = atomicAdd(&cnt[R], 1);                                   \
            if (k < CAND_CAP) {                                              \
                cand[R][k] = make_int2((JC), __float_as_int(wgt));           \
            } else {   /* exact fallback; never taken on plausible data */   \
                const float* whp = Wh + (size_t)(JC) * 64;                   \
                for (int cc = 0; cc < 64; ++cc)                              \
                    atomicAdd(&oaccL[R][cc], wgt * whp[cc]);                 \
            }                                                                \
        }                                                                    \
    }

    #pragma unroll 2
    for (int it = 0; it < 10; ++it) {
        const int j0 = it * 1024 + tid * 4;
        if (j0 < N_NODES) {
            const int wb = it * 32 + w * 8 + (lane >> 5);
            const unsigned w00 = bits[0][wb + 0] & rm0;
            const unsigned w01 = bits[0][wb + 2] & rm0;
            const unsigned w02 = bits[0][wb + 4] & rm0;
            const unsigned w03 = bits[0][wb + 6] & rm0;
            const unsigned w10 = bits[1][wb + 0] & rm1;
            const unsigned w11 = bits[1][wb + 2] & rm1;
            const unsigned w12 = bits[1][wb + 4] & rm1;
            const unsigned w13 = bits[1][wb + 6] & rm1;
            if (((w00 | w01 | w02 | w03 | w10 | w11 | w12 | w13) >> lb) & 1u) {
                float4 al4 = *(const float4*)(alp + j0);
                float4 be4 = *(const float4*)(bet + j0);
                PB_TEST(w00, A0, B0v, esrc0, cl0, 0, al4.x, be4.x, j0 + 0)
                PB_TEST(w10, A1, B1v, esrc1, cl1, 1, al4.x, be4.x, j0 + 0)
                PB_TEST(w01, A0, B0v, esrc0, cl0, 0, al4.y, be4.y, j0 + 1)
                PB_TEST(w11, A1, B1v, esrc1, cl1, 1, al4.y, be4.y, j0 + 1)
                PB_TEST(w02, A0, B0v, esrc0, cl0, 0, al4.z, be4.z, j0 + 2)
                PB_TEST(w12, A1, B1v, esrc1, cl1, 1, al4.z, be4.z, j0 + 2)
                PB_TEST(w03, A0, B0v, esrc0, cl0, 0, al4.w, be4.w, j0 + 3)
                PB_TEST(w13, A1, B1v, esrc1, cl1, 1, al4.w, be4.w, j0 + 3)
            }
        }
        if ((empty0 | empty1) && j0 < N_NODES) {   // block-uniform; dead for this data
            float4 t4 = *(const float4*)(tarr + j0);
            #pragma unroll
            for (int c = 0; c < 4; ++c) {
                float tv = (c == 0) ? t4.x : (c == 1) ? t4.y : (c == 2) ? t4.z : t4.w;
                float wv = invN - tv;
                if (wv > 0.0f) {
                    #pragma unroll
                    for (int r = 0; r < 2; ++r) {
                        if (r == 0 ? empty0 : empty1) {
                            int k = atomicAdd(&cnt[r], 1);
                            if (k < CAND_CAP) {
                                cand[r][k] = make_int2(j0 + c, __float_as_int(wv));
                            } else {
                                const float* whp = Wh + (size_t)(j0 + c) * 64;
                                for (int cc = 0; cc < 64; ++cc)
                                    atomicAdd(&oaccL[r][cc], wv * whp[cc]);
                            }
                        }
                    }
                }
            }
        }
    }
#undef PB_TEST

    // ---- one barrier, then batched consume (4-deep MLP) ----
    __syncthreads();
    const int M0 = min(cnt[0], CAND_CAP), M1 = min(cnt[1], CAND_CAP);

    int c0 = w;
    for (; c0 + 12 < M0; c0 += 16) {
        int2 cd0 = cand[0][c0];
        int2 cd1 = cand[0][c0 + 4];
        int2 cd2 = cand[0][c0 + 8];
        int2 cd3 = cand[0][c0 + 12];
        float v0 = Wh[(size_t)cd0.x * 64 + lane];   // 256B coalesced, L2-hit
        float v1 = Wh[(size_t)cd1.x * 64 + lane];
        float v2 = Wh[(size_t)cd2.x * 64 + lane];
        float v3 = Wh[(size_t)cd3.x * 64 + lane];
        oacc0 += __int_as_float(cd0.y) * v0;
        oacc0 += __int_as_float(cd1.y) * v1;
        oacc0 += __int_as_float(cd2.y) * v2;
        oacc0 += __int_as_float(cd3.y) * v3;
    }
    for (; c0 < M0; c0 += 4) {
        int2 cd = cand[0][c0];
        oacc0 += __int_as_float(cd.y) * Wh[(size_t)cd.x * 64 + lane];
    }
    int c1 = w;
    for (; c1 + 12 < M1; c1 += 16) {
        int2 cd0 = cand[1][c1];
        int2 cd1 = cand[1][c1 + 4];
        int2 cd2 = cand[1][c1 + 8];
        int2 cd3 = cand[1][c1 + 12];
        float v0 = Wh[(size_t)cd0.x * 64 + lane];
        float v1 = Wh[(size_t)cd1.x * 64 + lane];
        float v2 = Wh[(size_t)cd2.x * 64 + lane];
        float v3 = Wh[(size_t)cd3.x * 64 + lane];
        oacc1 += __int_as_float(cd0.y) * v0;
        oacc1 += __int_as_float(cd1.y) * v1;
        oacc1 += __int_as_float(cd2.y) * v2;
        oacc1 += __int_as_float(cd3.y) * v3;
    }
    for (; c1 < M1; c1 += 4) {
        int2 cd = cand[1][c1];
        oacc1 += __int_as_float(cd.y) * Wh[(size_t)cd.x * 64 + lane];
    }

    // epilogue: alias bits (2560 B >= 512 floats). Safe: the pre-consume
    // barrier guarantees all produce-phase reads of `bits` are done; consume
    // touches only cand/Wh.
    float* partB = (float*)bits;
    partB[tid]       = oacc0;
    partB[256 + tid] = oacc1;
    __syncthreads();
    if (w < 2) {
        const float* pb = partB + w * 256;
        float tot = pb[lane] + pb[64 + lane] + pb[128 + lane] + pb[192 + lane]
                  + oaccL[w][lane];
        out[(size_t)(i0 + w) * 64 + lane] = tot > 0.0f ? tot : expm1f(tot);   // elu, alpha=1
    }
}

// ---------------------------------------------------------------------------
extern "C" void kernel_launch(void* const* d_in, const int* in_sizes, int n_in,
                              void* d_out, int out_size, void* d_ws, size_t ws_size,
                              hipStream_t stream)
{
    const float* h     = (const float*)d_in[0];
    const float* W     = (const float*)d_in[1];
    const float* a_src = (const float*)d_in[2];
    const float* a_dst = (const float*)d_in[3];
    const float* hub   = (const float*)d_in[4];
    const int*   adj   = (const int*)d_in[5];
    float* ws  = (float*)d_ws;
    float* out = (float*)d_out;

    k1_gemm<<<625, 256, 0, stream>>>(h, W, a_src, a_dst, ws);
    k1b_prep<<<40, 256, 0, stream>>>(hub, ws);
    k2_fused<<<N_NODES / 2, 256, 0, stream>>>(adj, ws, out);
}

// Round 3
// 585.359 us; speedup vs baseline: 1.0705x; 1.0114x over previous
//
#include <hip/hip_runtime.h>
#include <math.h>

#define N_NODES 10000
#define IN_FEAT 512
#define OUT_FEAT 64
#define LRELU_ALPHA 0.2f
#define HUB_THRESH 0.01f
#define BITS_WORDS 320   // ceil(10000/32)=313, padded to 320 (10 iters x 32 words)
#define CAND_CAP 1024    // per-row full-row list; ~100 expected survivors; exact fallback on overflow
#define PREF_SLACK 0.9394131f   // exp(-0.0625): prefilter slack, must not false-reject

// workspace layout, in 32-bit words
#define WH_OFF   0          // Wh [10000*64]
#define ESRC_OFF 640000     // e_src [10000]
#define EDST_OFF 650000     // e_dst [10000]
#define T_OFF    660000     // t_j = hub[j]*0.01 [10000]
#define F1_OFF   670000     // exp(edst_j)
#define F2_OFF   680000     // exp(0.2*edst_j)
#define AL_OFF   690000     // alpha_j = F1_j / t_j
#define BE_OFF   700000     // beta_j  = F2_j / t_j

// ---------------------------------------------------------------------------
// Kernel 1: Wh = h @ W (10000x512x64), e_src = Wh@a_src, e_dst = Wh@a_dst,
// F1/F2/t/alpha/beta per row (k1b folded into epilogue).
// Register blocking: each thread owns a 4x4 outer-product block (4 rows x
// 4 cols) with 4-way k-split across waves. Per k4-step: 8 ds_read_b128 feed
// 64 FMAs (96 LDS cyc vs 128 VALU cyc) -> VALU-bound; previous mapping was
// 5 b128 per 16 FMAs (60 vs 32) -> LDS-pipe-bound ~40us. K-split partials
// reduced through LDS (aliases Ws after the final tile barrier).
// ---------------------------------------------------------------------------
__global__ __launch_bounds__(256) void k1_gemm(
    const float* __restrict__ h, const float* __restrict__ W,
    const float* __restrict__ a_src, const float* __restrict__ a_dst,
    const float* __restrict__ hub, float* __restrict__ ws)
{
    const int bx = blockIdx.x, tid = threadIdx.x;
    __shared__ __align__(16) float smem[5184];   // Ws[64][64] @0 (16KB), Hs[16][68] @4096; epilogue: red[4][16][68]
    float* Ws = smem;
    float* Hs = smem + 4096;
    const int ks = tid >> 6;          // k-split id == wave id, 0..3
    const int slot = tid & 63;
    const int rg = slot >> 4;         // row group: rows rg*4 .. rg*4+3
    const int cq = slot & 15;         // col quad:  cols cq*4 .. cq*4+3
    const int rowBase = bx * 16;      // 625*16 == 10000 exactly
    float4 acc0 = make_float4(0.f,0.f,0.f,0.f);
    float4 acc1 = make_float4(0.f,0.f,0.f,0.f);
    float4 acc2 = make_float4(0.f,0.f,0.f,0.f);
    float4 acc3 = make_float4(0.f,0.f,0.f,0.f);

    for (int k0 = 0; k0 < IN_FEAT; k0 += 64) {
        // stage Ws: W[k0..k0+63][0..63] = 4096 contiguous floats = 1024 float4
        const float4* __restrict__ W4 = (const float4*)(W + (size_t)k0 * 64);
        #pragma unroll
        for (int t = 0; t < 4; ++t) ((float4*)Ws)[tid + t * 256] = W4[tid + t * 256];
        // stage Hs: row hr=tid>>4, k-quad kq=tid&15 (row-major, stride 68)
        {
            const int hr = tid >> 4, kq = tid & 15;
            *(float4*)&Hs[hr * 68 + kq * 4] =
                *(const float4*)&h[(size_t)(rowBase + hr) * IN_FEAT + k0 + kq * 4];
        }
        __syncthreads();
        #pragma unroll
        for (int s = 0; s < 4; ++s) {
            const int kl = ks * 16 + s * 4;   // this wave's k-slice within the tile
            float4 h0 = *(const float4*)&Hs[(rg * 4 + 0) * 68 + kl];
            float4 h1 = *(const float4*)&Hs[(rg * 4 + 1) * 68 + kl];
            float4 h2 = *(const float4*)&Hs[(rg * 4 + 2) * 68 + kl];
            float4 h3 = *(const float4*)&Hs[(rg * 4 + 3) * 68 + kl];
            float4 w0 = *(const float4*)&Ws[(kl + 0) * 64 + cq * 4];
            float4 w1 = *(const float4*)&Ws[(kl + 1) * 64 + cq * 4];
            float4 w2 = *(const float4*)&Ws[(kl + 2) * 64 + cq * 4];
            float4 w3 = *(const float4*)&Ws[(kl + 3) * 64 + cq * 4];
            acc0.x += h0.x*w0.x + h0.y*w1.x + h0.z*w2.x + h0.w*w3.x;
            acc0.y += h0.x*w0.y + h0.y*w1.y + h0.z*w2.y + h0.w*w3.y;
            acc0.z += h0.x*w0.z + h0.y*w1.z + h0.z*w2.z + h0.w*w3.z;
            acc0.w += h0.x*w0.w + h0.y*w1.w + h0.z*w2.w + h0.w*w3.w;
            acc1.x += h1.x*w0.x + h1.y*w1.x + h1.z*w2.x + h1.w*w3.x;
            acc1.y += h1.x*w0.y + h1.y*w1.y + h1.z*w2.y + h1.w*w3.y;
            acc1.z += h1.x*w0.z + h1.y*w1.z + h1.z*w2.z + h1.w*w3.z;
            acc1.w += h1.x*w0.w + h1.y*w1.w + h1.z*w2.w + h1.w*w3.w;
            acc2.x += h2.x*w0.x + h2.y*w1.x + h2.z*w2.x + h2.w*w3.x;
            acc2.y += h2.x*w0.y + h2.y*w1.y + h2.z*w2.y + h2.w*w3.y;
            acc2.z += h2.x*w0.z + h2.y*w1.z + h2.z*w2.z + h2.w*w3.z;
            acc2.w += h2.x*w0.w + h2.y*w1.w + h2.z*w2.w + h2.w*w3.w;
            acc3.x += h3.x*w0.x + h3.y*w1.x + h3.z*w2.x + h3.w*w3.x;
            acc3.y += h3.x*w0.y + h3.y*w1.y + h3.z*w2.y + h3.w*w3.y;
            acc3.z += h3.x*w0.z + h3.y*w1.z + h3.z*w2.z + h3.w*w3.z;
            acc3.w += h3.x*w0.w + h3.y*w1.w + h3.z*w2.w + h3.w*w3.w;
        }
        __syncthreads();   // protects next-tile staging AND the epilogue alias
    }

    // ---- k-split reduction through LDS (red aliases Ws/Hs; stride 68) ----
    float* red = smem;   // [4][16][68]
    *(float4*)&red[ks * 1088 + (rg * 4 + 0) * 68 + cq * 4] = acc0;
    *(float4*)&red[ks * 1088 + (rg * 4 + 1) * 68 + cq * 4] = acc1;
    *(float4*)&red[ks * 1088 + (rg * 4 + 2) * 68 + cq * 4] = acc2;
    *(float4*)&red[ks * 1088 + (rg * 4 + 3) * 68 + cq * 4] = acc3;
    __syncthreads();

    {
        const int r = tid >> 4, c = tid & 15;       // wave-local: lane>>4==r%4 groups of 16
        float4 a0 = *(const float4*)&red[0 * 1088 + r * 68 + c * 4];
        float4 a1 = *(const float4*)&red[1 * 1088 + r * 68 + c * 4];
        float4 a2 = *(const float4*)&red[2 * 1088 + r * 68 + c * 4];
        float4 a3 = *(const float4*)&red[3 * 1088 + r * 68 + c * 4];
        float4 tot = make_float4(a0.x + a1.x + a2.x + a3.x,
                                 a0.y + a1.y + a2.y + a3.y,
                                 a0.z + a1.z + a2.z + a3.z,
                                 a0.w + a1.w + a2.w + a3.w);
        const int row = rowBase + r;
        *(float4*)&ws[WH_OFF + (size_t)row * 64 + c * 4] = tot;
        const float4 as4 = *(const float4*)&a_src[c * 4];
        const float4 ad4 = *(const float4*)&a_dst[c * 4];
        float s1 = tot.x * as4.x + tot.y * as4.y + tot.z * as4.z + tot.w * as4.w;
        float s2 = tot.x * ad4.x + tot.y * ad4.y + tot.z * ad4.z + tot.w * ad4.w;
        // reduce across the 16 lanes sharing a row (xor masks stay in-group)
        #pragma unroll
        for (int m = 1; m <= 8; m <<= 1) {
            s1 += __shfl_xor(s1, m, 64);
            s2 += __shfl_xor(s2, m, 64);
        }
        if (c == 0) {
            ws[ESRC_OFF + row] = s1;
            ws[EDST_OFF + row] = s2;
            // k1b folded in: per-j precompute off the final edst
            float F1 = __expf(s2);
            float F2 = __expf(0.2f * s2);
            float t  = hub[row] * HUB_THRESH;   // t==0 -> alpha/beta=+inf: prefilter passes, relu decides
            ws[T_OFF  + row] = t;
            ws[F1_OFF + row] = F1;
            ws[F2_OFF + row] = F2;
            ws[AL_OFF + row] = F1 / t;
            ws[BE_OFF + row] = F2 / t;
        }
    }
}

// ---------------------------------------------------------------------------
// Kernel 2 (fused, 2 rows/block): block b handles rows 2b, 2b+1.
// ALGEBRAIC CORE: exp(lrelu(esrc_i+edst_j)) = max(E1_i*F1_j, E2_i*F2_j)
// (exp is monotone; lrelu = max(s, 0.2s)), E1=exp(esrc), E2=exp(0.2 esrc).
// Pass A: stream both adj rows once (400 MB); per element: mul+max+masked-add
//   — ZERO exp calls. Bits via __ballot. ~at adj-BW roofline.
// Pass B: prefilter alpha_j > kappa*l/E1 || beta_j > kappa*l/E2 (per-j test
//   required: t unbounded below — R6 lesson). Survivors (rare) run the EXACT
//   original path p=exp(e-cl), wgt=p-t. Single list, one barrier, 4-deep
//   consume. LDS ~19.5 KB -> 8 blocks/CU.
// ---------------------------------------------------------------------------
__global__ __launch_bounds__(256) void k2_fused(
    const int* __restrict__ adj, const float* __restrict__ ws,
    float* __restrict__ out)
{
    const int b = blockIdx.x, tid = threadIdx.x;
    const int lane = tid & 63, w = tid >> 6;
    const int i0 = 2 * b, i1 = 2 * b + 1;
    __shared__ unsigned bits[2][BITS_WORDS];   // 2560 B; aliased as partB in epilogue
    __shared__ float partA[2][4];
    __shared__ int2  cand[2][CAND_CAP];        // 16 KB
    __shared__ int   cnt[2];
    __shared__ float oaccL[2][64];             // overflow accumulator (exact fallback)

    const float esrc0 = ws[ESRC_OFF + i0];
    const float esrc1 = ws[ESRC_OFF + i1];
    const float E1_0 = __expf(esrc0), E2_0 = __expf(0.2f * esrc0);
    const float E1_1 = __expf(esrc1), E2_1 = __expf(0.2f * esrc1);
    const float R0 = E2_0 / E1_0, R1 = E2_1 / E1_1;   // = exp(-0.8*esrc)
    const int4*   __restrict__ arow0 = (const int4*)(adj + (size_t)i0 * N_NODES);
    const int4*   __restrict__ arow1 = (const int4*)(adj + (size_t)i1 * N_NODES);
    const float4* __restrict__ F14   = (const float4*)(ws + F1_OFF);
    const float4* __restrict__ F24   = (const float4*)(ws + F2_OFF);
    float acc0 = 0.f, acc1 = 0.f;

    if (tid < 2) cnt[tid] = 0;                 // visible after pass-A barrier
    if (tid < 128) ((float*)oaccL)[tid] = 0.f;

    // ---- Pass A: acc_r = sum_{adj} max(F1_j, R_r*F2_j); l_r = E1_r*acc_r ----
#define PA_BODY(IT, A0v, A1v, F1v, F2v)                                      \
    {                                                                        \
        float v0, v1;                                                        \
        unsigned long long B0, B1, B2, B3, B4, B5, B6, B7;                   \
        v0 = fmaxf((F1v).x, R0 * (F2v).x);                                   \
        v1 = fmaxf((F1v).x, R1 * (F2v).x);                                   \
        if ((A0v).x > 0) acc0 += v0;                                         \
        if ((A1v).x > 0) acc1 += v1;                                         \
        B0 = __ballot((A0v).x > 0);                                          \
        B4 = __ballot((A1v).x > 0);                                          \
        v0 = fmaxf((F1v).y, R0 * (F2v).y);                                   \
        v1 = fmaxf((F1v).y, R1 * (F2v).y);                                   \
        if ((A0v).y > 0) acc0 += v0;                                         \
        if ((A1v).y > 0) acc1 += v1;                                         \
        B1 = __ballot((A0v).y > 0);                                          \
        B5 = __ballot((A1v).y > 0);                                          \
        v0 = fmaxf((F1v).z, R0 * (F2v).z);                                   \
        v1 = fmaxf((F1v).z, R1 * (F2v).z);                                   \
        if ((A0v).z > 0) acc0 += v0;                                         \
        if ((A1v).z > 0) acc1 += v1;                                         \
        B2 = __ballot((A0v).z > 0);                                          \
        B6 = __ballot((A1v).z > 0);                                          \
        v0 = fmaxf((F1v).w, R0 * (F2v).w);                                   \
        v1 = fmaxf((F1v).w, R1 * (F2v).w);                                   \
        if ((A0v).w > 0) acc0 += v0;                                         \
        if ((A1v).w > 0) acc1 += v1;                                         \
        B3 = __ballot((A0v).w > 0);                                          \
        B7 = __ballot((A1v).w > 0);                                          \
        if (lane < 8) {                                                      \
            /* lane -> (r = lane>>2, c = lane&3); ballots are wave-uniform */\
            unsigned long long v =                                           \
                (lane & 4) ? ((lane & 2) ? ((lane & 1) ? B7 : B6)            \
                                         : ((lane & 1) ? B5 : B4))           \
                           : ((lane & 2) ? ((lane & 1) ? B3 : B2)            \
                                         : ((lane & 1) ? B1 : B0));          \
            *((unsigned long long*)&bits[lane >> 2][0] +                     \
              ((IT) * 16 + w * 4 + (lane & 3))) = v;                         \
        }                                                                    \
    }

    // iters 0..8: max j = 8*1024 + 255*4 + 3 = 9215 < 10000 -> unguarded
    #pragma unroll 3
    for (int it = 0; it < 9; ++it) {
        int4   a0 = arow0[it * 256 + tid];
        int4   a1 = arow1[it * 256 + tid];
        float4 f1 = F14[it * 256 + tid];
        float4 f2 = F24[it * 256 + tid];
        PA_BODY(it, a0, a1, f1, f2)
    }
    {   // tail it=9: guarded loads, zeros for OOB lanes so ballot/write are full-wave
        const int j0t = 9216 + tid * 4;
        int4   a0 = make_int4(0, 0, 0, 0), a1 = make_int4(0, 0, 0, 0);
        float4 f1 = make_float4(0.f, 0.f, 0.f, 0.f), f2 = f1;
        if (j0t < N_NODES) {
            a0 = arow0[9 * 256 + tid];
            a1 = arow1[9 * 256 + tid];
            f1 = F14[9 * 256 + tid];
            f2 = F24[9 * 256 + tid];
        }
        PA_BODY(9, a0, a1, f1, f2)
    }
#undef PA_BODY

    #pragma unroll
    for (int m = 32; m; m >>= 1) {
        acc0 += __shfl_xor(acc0, m, 64);
        acc1 += __shfl_xor(acc1, m, 64);
    }
    if (lane == 0) { partA[0][w] = acc0; partA[1][w] = acc1; }
    __syncthreads();
    const float l0 = E1_0 * (partA[0][0] + partA[0][1] + partA[0][2] + partA[0][3]);
    const float l1 = E1_1 * (partA[1][0] + partA[1][1] + partA[1][2] + partA[1][3]);

    // ---- Pass B: produce (no barriers) ----
    const bool empty0 = (l0 == 0.0f), empty1 = (l1 == 0.0f);  // rows w/o neighbors: uniform 1/N
    const float cl0 = empty0 ? 0.0f : logf(l0);
    const float cl1 = empty1 ? 0.0f : logf(l1);
    const float A0 = PREF_SLACK * l0 / E1_0, B0v = PREF_SLACK * l0 / E2_0;
    const float A1 = PREF_SLACK * l1 / E1_1, B1v = PREF_SLACK * l1 / E2_1;
    const float invN = 1.0f / (float)N_NODES;
    const float* __restrict__ tarr = ws + T_OFF;
    const float* __restrict__ edst = ws + EDST_OFF;
    const float* __restrict__ alp  = ws + AL_OFF;
    const float* __restrict__ bet  = ws + BE_OFF;
    const float* __restrict__ Wh   = ws + WH_OFF;
    float oacc0 = 0.f, oacc1 = 0.f;
    const unsigned rm0 = empty0 ? 0u : 0xffffffffu;
    const unsigned rm1 = empty1 ? 0u : 0xffffffffu;
    const unsigned lb = lane & 31;

#define PB_TEST(WROW, Athr, Bthr, ESRC, CL, R, ALc, BEc, JC)                 \
    if ((((WROW) >> lb) & 1u) && ((ALc) > (Athr) || (BEc) > (Bthr))) {       \
        float ed = edst[JC];                                                 \
        float s = (ESRC) + ed;                                               \
        float e = fmaxf(s, LRELU_ALPHA * s);                                 \
        float p = __expf(e - (CL));                     /* = exp(e)/l */     \
        float wgt = p - tarr[JC];                       /* exact relu */     \
        if (wgt > 0.0f) {                                                    \
            int k = atomicAdd(&cnt[R], 1);                                   \
            if (k < CAND_CAP) {                                              \
                cand[R][k] = make_int2((JC), __float_as_int(wgt));           \
            } else {   /* exact fallback; never taken on plausible data */   \
                const float* whp = Wh + (size_t)(JC) * 64;                   \
                for (int cc = 0; cc < 64; ++cc)                              \
                    atomicAdd(&oaccL[R][cc], wgt * whp[cc]);                 \
            }                                                                \
        }                                                                    \
    }

    #pragma unroll 2
    for (int it = 0; it < 10; ++it) {
        const int j0 = it * 1024 + tid * 4;
        if (j0 < N_NODES) {
            const int wb = it * 32 + w * 8 + (lane >> 5);
            const unsigned w00 = bits[0][wb + 0] & rm0;
            const unsigned w01 = bits[0][wb + 2] & rm0;
            const unsigned w02 = bits[0][wb + 4] & rm0;
            const unsigned w03 = bits[0][wb + 6] & rm0;
            const unsigned w10 = bits[1][wb + 0] & rm1;
            const unsigned w11 = bits[1][wb + 2] & rm1;
            const unsigned w12 = bits[1][wb + 4] & rm1;
            const unsigned w13 = bits[1][wb + 6] & rm1;
            if (((w00 | w01 | w02 | w03 | w10 | w11 | w12 | w13) >> lb) & 1u) {
                float4 al4 = *(const float4*)(alp + j0);
                float4 be4 = *(const float4*)(bet + j0);
                PB_TEST(w00, A0, B0v, esrc0, cl0, 0, al4.x, be4.x, j0 + 0)
                PB_TEST(w10, A1, B1v, esrc1, cl1, 1, al4.x, be4.x, j0 + 0)
                PB_TEST(w01, A0, B0v, esrc0, cl0, 0, al4.y, be4.y, j0 + 1)
                PB_TEST(w11, A1, B1v, esrc1, cl1, 1, al4.y, be4.y, j0 + 1)
                PB_TEST(w02, A0, B0v, esrc0, cl0, 0, al4.z, be4.z, j0 + 2)
                PB_TEST(w12, A1, B1v, esrc1, cl1, 1, al4.z, be4.z, j0 + 2)
                PB_TEST(w03, A0, B0v, esrc0, cl0, 0, al4.w, be4.w, j0 + 3)
                PB_TEST(w13, A1, B1v, esrc1, cl1, 1, al4.w, be4.w, j0 + 3)
            }
        }
        if ((empty0 | empty1) && j0 < N_NODES) {   // block-uniform; dead for this data
            float4 t4 = *(const float4*)(tarr + j0);
            #pragma unroll
            for (int c = 0; c < 4; ++c) {
                float tv = (c == 0) ? t4.x : (c == 1) ? t4.y : (c == 2) ? t4.z : t4.w;
                float wv = invN - tv;
                if (wv > 0.0f) {
                    #pragma unroll
                    for (int r = 0; r < 2; ++r) {
                        if (r == 0 ? empty0 : empty1) {
                            int k = atomicAdd(&cnt[r], 1);
                            if (k < CAND_CAP) {
                                cand[r][k] = make_int2(j0 + c, __float_as_int(wv));
                            } else {
                                const float* whp = Wh + (size_t)(j0 + c) * 64;
                                for (int cc = 0; cc < 64; ++cc)
                                    atomicAdd(&oaccL[r][cc], wv * whp[cc]);
                            }
                        }
                    }
                }
            }
        }
    }
#undef PB_TEST

    // ---- one barrier, then batched consume (4-deep MLP) ----
    __syncthreads();
    const int M0 = min(cnt[0], CAND_CAP), M1 = min(cnt[1], CAND_CAP);

    int c0 = w;
    for (; c0 + 12 < M0; c0 += 16) {
        int2 cd0 = cand[0][c0];
        int2 cd1 = cand[0][c0 + 4];
        int2 cd2 = cand[0][c0 + 8];
        int2 cd3 = cand[0][c0 + 12];
        float v0 = Wh[(size_t)cd0.x * 64 + lane];   // 256B coalesced, L2-hit
        float v1 = Wh[(size_t)cd1.x * 64 + lane];
        float v2 = Wh[(size_t)cd2.x * 64 + lane];
        float v3 = Wh[(size_t)cd3.x * 64 + lane];
        oacc0 += __int_as_float(cd0.y) * v0;
        oacc0 += __int_as_float(cd1.y) * v1;
        oacc0 += __int_as_float(cd2.y) * v2;
        oacc0 += __int_as_float(cd3.y) * v3;
    }
    for (; c0 < M0; c0 += 4) {
        int2 cd = cand[0][c0];
        oacc0 += __int_as_float(cd.y) * Wh[(size_t)cd.x * 64 + lane];
    }
    int c1 = w;
    for (; c1 + 12 < M1; c1 += 16) {
        int2 cd0 = cand[1][c1];
        int2 cd1 = cand[1][c1 + 4];
        int2 cd2 = cand[1][c1 + 8];
        int2 cd3 = cand[1][c1 + 12];
        float v0 = Wh[(size_t)cd0.x * 64 + lane];
        float v1 = Wh[(size_t)cd1.x * 64 + lane];
        float v2 = Wh[(size_t)cd2.x * 64 + lane];
        float v3 = Wh[(size_t)cd3.x * 64 + lane];
        oacc1 += __int_as_float(cd0.y) * v0;
        oacc1 += __int_as_float(cd1.y) * v1;
        oacc1 += __int_as_float(cd2.y) * v2;
        oacc1 += __int_as_float(cd3.y) * v3;
    }
    for (; c1 < M1; c1 += 4) {
        int2 cd = cand[1][c1];
        oacc1 += __int_as_float(cd.y) * Wh[(size_t)cd.x * 64 + lane];
    }

    // epilogue: alias bits (2560 B >= 512 floats). Safe: the pre-consume
    // barrier guarantees all produce-phase reads of `bits` are done; consume
    // touches only cand/Wh.
    float* partB = (float*)bits;
    partB[tid]       = oacc0;
    partB[256 + tid] = oacc1;
    __syncthreads();
    if (w < 2) {
        const float* pb = partB + w * 256;
        float tot = pb[lane] + pb[64 + lane] + pb[128 + lane] + pb[192 + lane]
                  + oaccL[w][lane];
        out[(size_t)(i0 + w) * 64 + lane] = tot > 0.0f ? tot : expm1f(tot);   // elu, alpha=1
    }
}

// ---------------------------------------------------------------------------
extern "C" void kernel_launch(void* const* d_in, const int* in_sizes, int n_in,
                              void* d_out, int out_size, void* d_ws, size_t ws_size,
                              hipStream_t stream)
{
    const float* h     = (const float*)d_in[0];
    const float* W     = (const float*)d_in[1];
    const float* a_src = (const float*)d_in[2];
    const float* a_dst = (const float*)d_in[3];
    const float* hub   = (const float*)d_in[4];
    const int*   adj   = (const int*)d_in[5];
    float* ws  = (float*)d_ws;
    float* out = (float*)d_out;

    k1_gemm<<<625, 256, 0, stream>>>(h, W, a_src, a_dst, hub, ws);
    k2_fused<<<N_NODES / 2, 256, 0, stream>>>(adj, ws, out);
}